// Round 12
// baseline (4562.630 us; speedup 1.0000x reference)
//
#include <hip/hip_runtime.h>
#include <hip/hip_bf16.h>

#define NG 4096
#define NP 512
#define TT 100
#define NCOL 4608            // 4096 z-cols + 512 dec-cols
#define NKS 8                // K-splits (512 each)
#define NBLK 288             // persistent grid = strips

typedef __bf16  bf16x8 __attribute__((ext_vector_type(8)));
typedef float   f32x4  __attribute__((ext_vector_type(4)));
typedef __hip_bfloat16 bf;
typedef unsigned short u16;

// bf16(0.1) = 0.10009765625, bf16(0.9) = 0.8984375 — the reference's weakly-
// typed python scalars are demoted to bf16 before the elementwise ops.
#define ALPHA_BF 0.10009765625f
#define BETA_BF  0.8984375f

__device__ __forceinline__ bf16x8 ldfrag(const bf* p) {
  return *reinterpret_cast<const bf16x8*>(p);
}
__device__ __forceinline__ f32x4 mfma16(bf16x8 a, bf16x8 b, f32x4 c) {
  return __builtin_amdgcn_mfma_f32_16x16x32_bf16(a, b, c, 0, 0, 0);
}
__device__ __forceinline__ float ldin(const void* p, long i, int isf) {
  return isf ? ((const float*)p)[i] : __bfloat162float(((const bf*)p)[i]);
}
// round-to-nearest-even through bf16 and back (emulates XLA bf16 elementwise)
__device__ __forceinline__ float bfr(float x) {
  return __bfloat162float(__float2bfloat16(x));
}
// Fragment-major index for the hidden state Q[kk][mt][lane][8]:
// element (m, c):  kk=c>>5, quad=(c>>3)&3, j=c&7, mt=m>>4, l16=m&15.
__device__ __forceinline__ long qidx(int m, int c) {
  int kk = c >> 5, qd = (c >> 3) & 3, j = c & 7;
  int mt = m >> 4, lm = m & 15;
  return (((long)kk * 4 + mt) * 64 + (qd * 16 + lm)) * 8 + j;
}

// Ticket grid-barrier: cumulative arrivals (never reset -> no reset race),
// monotonic generation. it = barrier index (0-based). All NBLK blocks are
// co-resident by construction (launch_bounds cap -> >=2 blocks/CU capacity).
__device__ __forceinline__ void gridbar(int* cnt, int* gen, int it) {
  __syncthreads();
  if (threadIdx.x == 0) {
    __threadfence();                              // release this block's writes
    int my = atomicAdd(cnt, 1);
    if (my == NBLK * (it + 1) - 1) {
      atomicAdd(gen, 1);                          // last arriver flips
    } else {
      while (atomicAdd(gen, 0) <= it)             // atomic read, device scope
        __builtin_amdgcn_s_sleep(8);
    }
    __threadfence();                              // acquire others' writes
  }
  __syncthreads();
}

// ---------------------------------------------------------------------------
// Probe: fp32 (flag=1) vs bf16 (flag=0) inputs. Verified many rounds.
// ---------------------------------------------------------------------------
__global__ void probe_kernel(const u16* __restrict__ w, int* __restrict__ flag) {
  int lane = threadIdx.x;
  int okall = 1, cntb = 0;
#pragma unroll
  for (int j = 0; j < 4; ++j) {
    u16 x = w[2 * (lane * 4 + j)];
    int e = (x >> 7) & 0xFF;
    int bok = (e >= 60 && e <= 126);
    int zok = (e == 0);
    okall &= (bok | zok);
    cntb += bok;
  }
  unsigned long long b1 = __ballot(okall != 0);
  unsigned long long b2 = __ballot(cntb >= 3);
  if (lane == 0)
    *flag = (b1 == ~0ull && __popcll(b2) >= 48) ? 0 : 1;
}

// ---------------------------------------------------------------------------
// cvt_pack: fragment-major weight panels from [W_hh | W_dec], vectorized:
// one 8-elem group per thread = one 16B load+store.
// bf16 mode: PH is an exact permuted copy; PL is never read -> skip stores.
// ---------------------------------------------------------------------------
__global__ __launch_bounds__(256) void cvt_pack_kernel(
    const void* __restrict__ Whh, const void* __restrict__ Wdec,
    bf* __restrict__ PH, bf* __restrict__ PL,
    const int* __restrict__ flag) {
  int isf = *flag;
  long n8 = (long)NCOL * NG / 8;             // 2,359,296 groups
  long i = (long)blockIdx.x * 256 + threadIdx.x;
  long stride = (long)gridDim.x * 256;
  for (; i < n8; i += stride) {
    int lane = (int)(i & 63);
    int kk   = (int)((i >> 6) & 127);
    int strip= (int)(i >> 13);
    int col  = strip * 16 + (lane & 15);
    int k0   = kk * 32 + (lane >> 4) * 8;
    const void* W = (col < NG) ? Whh : Wdec;
    long src = (long)((col < NG) ? col : col - NG) * NG + k0;
    if (isf) {
      const float* ps = (const float*)W + src;
      float4 x = *(const float4*)ps, y = *(const float4*)(ps + 4);
      float xs[8] = {x.x, x.y, x.z, x.w, y.x, y.y, y.z, y.w};
      bf16x8 h, l;
#pragma unroll
      for (int j = 0; j < 8; ++j) {
        bf hh = __float2bfloat16(xs[j]);
        bf ll = __float2bfloat16(xs[j] - __bfloat162float(hh));
        h[j] = *reinterpret_cast<__bf16*>(&hh);
        l[j] = *reinterpret_cast<__bf16*>(&ll);
      }
      *reinterpret_cast<bf16x8*>(PH + i * 8) = h;
      *reinterpret_cast<bf16x8*>(PL + i * 8) = l;
    } else {
      *reinterpret_cast<bf16x8*>(PH + i * 8) =
          *reinterpret_cast<const bf16x8*>((const bf*)W + src);
      // PL untouched: bf16-mode GEMM never reads it.
    }
  }
}

// ---------------------------------------------------------------------------
// init: h0 = p0 @ W_init.T -> Q-layout hi/lo; zero va/zp + barrier vars.
// Coalesced wave-dot, 8 rows/wave. Arithmetic identical to verified.
// ---------------------------------------------------------------------------
__global__ __launch_bounds__(256) void init_kernel(
    const void* __restrict__ p0, const void* __restrict__ Winit,
    const int* __restrict__ flag,
    bf* __restrict__ hi0, bf* __restrict__ lo0,
    float* __restrict__ va, float* __restrict__ zp,
    int* __restrict__ sync)
{
  if (blockIdx.x == 0 && threadIdx.x == 0) { sync[0] = 0; sync[16] = 0; }
  int isf = *flag;
  int g = blockIdx.x * 4 + (threadIdx.x >> 6);   // global wave id 0..32767
  int lane = threadIdx.x & 63;
  int b  = g >> 9;                               // 0..63 (wave-uniform)
  int n0 = g & 511;                              // base row
  float pf[8];
  if (isf) {
    const float* pp = (const float*)p0 + (long)b * NP + lane * 8;
    float4 x = *(const float4*)pp, y = *(const float4*)(pp + 4);
    pf[0]=x.x; pf[1]=x.y; pf[2]=x.z; pf[3]=x.w;
    pf[4]=y.x; pf[5]=y.y; pf[6]=y.z; pf[7]=y.w;
  } else {
    bf16x8 a = ldfrag((const bf*)p0 + (long)b * NP + lane * 8);
#pragma unroll
    for (int j = 0; j < 8; ++j) pf[j] = (float)a[j];
  }
#pragma unroll
  for (int it = 0; it < 8; ++it) {
    int n = n0 + (it << 9);                      // 0..4095
    float acc;
    if (isf) {
      const float* pw = (const float*)Winit + (long)n * NP + lane * 8;
      float4 x = *(const float4*)pw, y = *(const float4*)(pw + 4);
      acc = pf[0]*x.x + pf[1]*x.y + pf[2]*x.z + pf[3]*x.w
          + pf[4]*y.x + pf[5]*y.y + pf[6]*y.z + pf[7]*y.w;
    } else {
      bf16x8 wv = ldfrag((const bf*)Winit + (long)n * NP + lane * 8);
      acc = 0.f;
#pragma unroll
      for (int j = 0; j < 8; ++j) acc += pf[j] * (float)wv[j];
    }
#pragma unroll
    for (int s = 32; s >= 1; s >>= 1) acc += __shfl_xor(acc, s, 64);
    if (lane == 0) {
      bf h = __float2bfloat16(acc);
      float lo = isf ? (acc - __bfloat162float(h)) : 0.f;
      long q = qidx(b, n);
      hi0[q] = h;
      lo0[q] = __float2bfloat16(lo);
      long idx = (long)b * NG + n;
      va[idx] = 0.f;
      zp[idx] = 0.f;
    }
  }
}

// ---------------------------------------------------------------------------
// loop: PERSISTENT kernel — all 101 steps in ONE dispatch. 288 blocks x 512.
// Block = strip; wave = ks (8 K-splits); each wave 4 acc chains (full 64 m).
// Per-acc MFMA chain order identical to the verified split kernels; in-block
// LDS reduce in ks order 0..7 (same fp32 sum order); verified-s2 epilogue
// inline; ticket grid-barrier between steps (1/step, fences only there —
// not R8's 2304 inline fences). Rationale: exec is ~3-6 us/step by traffic
// arithmetic yet every multi-dispatch structure pays ~30 us/step -> the
// invariant is ~14 us per graph-node dispatch overhead x 202 nodes. This
// removes 201 dispatch boundaries.
// launch_bounds(512,4): VGPR<=128 -> >=2 blocks/CU capacity (LDS 32KB -> 5;
// waves 8 -> 4) => all 288 blocks co-resident; spin barrier is deadlock-free.
// ---------------------------------------------------------------------------
__global__ __launch_bounds__(512, 4) void loop_kernel(
    bf* __restrict__ hi0, bf* __restrict__ hi1,
    bf* __restrict__ lo0, bf* __restrict__ lo1,
    float* __restrict__ va, float* __restrict__ zp,
    const bf* __restrict__ PH, const bf* __restrict__ PL,
    const void* __restrict__ Wih, const void* __restrict__ vin,
    const int* __restrict__ flag, void* __restrict__ out,
    int* __restrict__ sync)
{
  int strip = blockIdx.x;              // 0..287
  bool isdec = (strip >= 256);
  int isf = *flag;
  int tid  = threadIdx.x;
  int ks   = tid >> 6;                 // 0..7
  int lane = tid & 63;
  int quad = lane >> 4, l16 = lane & 15;
  int* cnt = sync;                     // arrivals (cumulative)
  int* gen = sync + 16;                // generation (separate cacheline)

  const bf* pB  = PH + ((long)strip * 128 + ks * 16) * 512 + lane * 8;
  const bf* pBl = PL + ((long)strip * 128 + ks * 16) * 512 + lane * 8;

  __shared__ float red[NKS][64][16];   // 32 KB

  for (int t = 0; t <= TT; ++t) {
    const bf* Qh = (t & 1) ? hi1 : hi0;
    const bf* Ql = (t & 1) ? lo1 : lo0;
    bf* hN = (t & 1) ? hi0 : hi1;
    bf* lN = (t & 1) ? lo0 : lo1;
    bool active = isdec ? (t != 0) : (t != TT);

    if (active) {
      const bf* pA = Qh + (long)ks * 32768 + lane * 8;
      f32x4 acc0 = {0.f,0.f,0.f,0.f}, acc1 = acc0, acc2 = acc0, acc3 = acc0;
      if (isf) {
        const bf* pAl = Ql + (long)ks * 32768 + lane * 8;
#pragma unroll 2
        for (int i = 0; i < 16; ++i) {
          bf16x8 bh = ldfrag(pB  + i * 512);
          bf16x8 bl = ldfrag(pBl + i * 512);
          const bf* ah = pA  + i * 2048;
          const bf* al = pAl + i * 2048;
          bf16x8 a0 = ldfrag(ah);
          bf16x8 a1 = ldfrag(ah + 512);
          bf16x8 a2 = ldfrag(ah + 1024);
          bf16x8 a3 = ldfrag(ah + 1536);
          bf16x8 l0 = ldfrag(al);
          bf16x8 l1 = ldfrag(al + 512);
          bf16x8 l2 = ldfrag(al + 1024);
          bf16x8 l3 = ldfrag(al + 1536);
          acc0 = mfma16(a0, bh, acc0); acc0 = mfma16(l0, bh, acc0); acc0 = mfma16(a0, bl, acc0);
          acc1 = mfma16(a1, bh, acc1); acc1 = mfma16(l1, bh, acc1); acc1 = mfma16(a1, bl, acc1);
          acc2 = mfma16(a2, bh, acc2); acc2 = mfma16(l2, bh, acc2); acc2 = mfma16(a2, bl, acc2);
          acc3 = mfma16(a3, bh, acc3); acc3 = mfma16(l3, bh, acc3); acc3 = mfma16(a3, bl, acc3);
        }
      } else {
#pragma unroll 4
        for (int i = 0; i < 16; ++i) {
          bf16x8 bh = ldfrag(pB + i * 512);
          const bf* ah = pA + i * 2048;
          acc0 = mfma16(ldfrag(ah),        bh, acc0);
          acc1 = mfma16(ldfrag(ah + 512),  bh, acc1);
          acc2 = mfma16(ldfrag(ah + 1024), bh, acc2);
          acc3 = mfma16(ldfrag(ah + 1536), bh, acc3);
        }
      }
      // C/D layout (verified): col=l16, row=quad*4+r; m = mt*16 + quad*4 + r.
#pragma unroll
      for (int mt = 0; mt < 4; ++mt) {
        f32x4 a = (mt == 0) ? acc0 : (mt == 1) ? acc1 : (mt == 2) ? acc2 : acc3;
#pragma unroll
        for (int r = 0; r < 4; ++r)
          red[ks][mt * 16 + quad * 4 + r][l16] = a[r];
      }
    }
    __syncthreads();

    if (active) {
      // epilogue: 1024 elems (64 m x 16 cols), 2 per thread — verified s2 math.
#pragma unroll
      for (int half = 0; half < 2; ++half) {
        int e = half * 512 + tid;      // 0..1023
        int m   = e >> 4;              // batch row 0..63
        int c16 = e & 15;
        int c = strip * 16 + c16;      // column 0..4607
        float z = 0.f;
#pragma unroll
        for (int k2 = 0; k2 < NKS; ++k2)   // same ks order as verified
          z += red[k2][m][c16];

        if (isdec) {
          long o = ((long)m * TT + (t - 1)) * NP + (c - NG);
          if (isf) ((float*)out)[o] = z;
          else     ((bf*)out)[o]    = __float2bfloat16(z);
        } else {
          float w0 = ldin(Wih, 2L * c, isf);
          float w1 = ldin(Wih, 2L * c + 1, isf);
          float v0 = ldin(vin, ((long)m * TT + t) * 2, isf);
          float v1 = ldin(vin, ((long)m * TT + t) * 2 + 1, isf);
          long idx = (long)m * NG + c;
          float vao = va[idx], zpo = zp[idx];
          if (isf) {
            z += v0 * w0 + v1 * w1;
            z -= 0.1f * vao;                      // subtract uses OLD va
            va[idx] = vao + 0.9f * (zpo - vao);   // adaptation uses OLD zp
            zp[idx] = z;                          // z_prev = post-subtraction z
            float s = fmaxf(z, 0.f);
            bf sh = __float2bfloat16(s);
            long q = qidx(m, c);
            hN[q] = sh;
            lN[q] = __float2bfloat16(s - __bfloat162float(sh));
          } else {
            // stepwise bf16 requantization (matches XLA bf16 ref; verified)
            float zmm = bfr(z);                   // bf16(h @ Whh.T)
            float zv  = bfr(v0 * w0 + v1 * w1);   // bf16(v_t @ Wih.T)
            float z0  = bfr(zmm + zv);            // bf16 add
            float sub = bfr(ALPHA_BF * vao);      // bf16(bf16(0.1) * va)
            float z1  = bfr(z0 - sub);            // post-subtraction z (bf16)
            float d   = bfr(zpo - vao);           // bf16(zp - va)
            float mm  = bfr(BETA_BF * d);         // bf16(bf16(0.9) * d)
            va[idx]   = bfr(vao + mm);
            zp[idx]   = z1;
            float s = fmaxf(z1, 0.f);
            long q = qidx(m, c);
            hN[q] = __float2bfloat16(s);          // exact
            lN[q] = __float2bfloat16(0.f);        // ref carries NO extra bits
          }
        }
      }
    }
    gridbar(cnt, gen, t);              // all 288 blocks, every t — no skips
  }
}

// ---------------------------------------------------------------------------
extern "C" void kernel_launch(void* const* d_in, const int* in_sizes, int n_in,
                              void* d_out, int out_size, void* d_ws, size_t ws_size,
                              hipStream_t stream) {
  const void* v     = d_in[0];   // [64,100,2]
  const void* p0    = d_in[1];   // [64,512]
  const void* Winit = d_in[2];   // [4096,512]
  const void* Wih   = d_in[3];   // [4096,2]
  const void* Whh   = d_in[4];   // [4096,4096]
  const void* Wdec  = d_in[5];   // [512,4096]

  size_t off = 0;
  char* w = (char*)d_ws;
  int*   flag = (int*)(w + off);          off += 64;
  bf*    PH   = (bf*)(w + off);           off += (size_t)NCOL * NG * 2;  // 37.75 MB
  bf*    PL   = (bf*)(w + off);           off += (size_t)NCOL * NG * 2;
  bf* hi0 = (bf*)(w + off);               off += (size_t)64 * NG * 2;
  bf* hi1 = (bf*)(w + off);               off += (size_t)64 * NG * 2;
  bf* lo0 = (bf*)(w + off);               off += (size_t)64 * NG * 2;
  bf* lo1 = (bf*)(w + off);               off += (size_t)64 * NG * 2;
  float* va   = (float*)(w + off);        off += (size_t)64 * NG * 4;
  float* zp   = (float*)(w + off);        off += (size_t)64 * NG * 4;
  int*   sync = (int*)(w + off);          off += 128;

  if (ws_size < off) return;

  probe_kernel<<<1, 64, 0, stream>>>((const u16*)Whh, flag);
  cvt_pack_kernel<<<9216, 256, 0, stream>>>(Whh, Wdec, PH, PL, flag);
  init_kernel<<<8192, 256, 0, stream>>>(p0, Winit, flag, hi0, lo0, va, zp, sync);
  loop_kernel<<<NBLK, 512, 0, stream>>>(hi0, hi1, lo0, lo1, va, zp,
                                        PH, PL, Wih, v, flag, d_out, sync);
}

// Round 13
// 4461.579 us; speedup vs baseline: 1.0226x; 1.0226x over previous
//
#include <hip/hip_runtime.h>
#include <hip/hip_bf16.h>

#define NG 4096
#define NP 512
#define TT 100
#define NCOL 4608            // 4096 z-cols + 512 dec-cols
#define NKS 8                // K-splits (512 each)
#define NBLK 256             // persistent grid: 1 block/CU, co-resident

typedef __bf16  bf16x8 __attribute__((ext_vector_type(8)));
typedef float   f32x4  __attribute__((ext_vector_type(4)));
typedef __hip_bfloat16 bf;
typedef unsigned short u16;

#define ALPHA_BF 0.10009765625f   // bf16(0.1)
#define BETA_BF  0.8984375f       // bf16(0.9)

__device__ __forceinline__ bf16x8 ldfrag(const bf* p) {
  return *reinterpret_cast<const bf16x8*>(p);
}
__device__ __forceinline__ f32x4 mfma16(bf16x8 a, bf16x8 b, f32x4 c) {
  return __builtin_amdgcn_mfma_f32_16x16x32_bf16(a, b, c, 0, 0, 0);
}
__device__ __forceinline__ float ldin(const void* p, long i, int isf) {
  return isf ? ((const float*)p)[i] : __bfloat162float(((const bf*)p)[i]);
}
__device__ __forceinline__ float bfr(float x) {
  return __bfloat162float(__float2bfloat16(x));
}
// Fragment-major index for the hidden state Q[kk][mt][lane][8] (verified).
__device__ __forceinline__ long qidx(int m, int c) {
  int kk = c >> 5, qd = (c >> 3) & 3, j = c & 7;
  int mt = m >> 4, lm = m & 15;
  return (((long)kk * 4 + mt) * 64 + (qd * 16 + lm)) * 8 + j;
}

// Ticket grid-barrier (R12-proven, incl. cross-XCD visibility via fences).
__device__ __forceinline__ void gridbar(int* cnt, int* gen, int it) {
  __syncthreads();
  if (threadIdx.x == 0) {
    __threadfence();
    int my = atomicAdd(cnt, 1);
    if (my == NBLK * (it + 1) - 1) {
      atomicAdd(gen, 1);
    } else {
      while (atomicAdd(gen, 0) <= it)
        __builtin_amdgcn_s_sleep(8);
    }
    __threadfence();
  }
  __syncthreads();
}

// ---------------------------------------------------------------------------
// Probe: fp32 (flag=1) vs bf16 (flag=0) inputs. Verified many rounds.
// ---------------------------------------------------------------------------
__global__ void probe_kernel(const u16* __restrict__ w, int* __restrict__ flag) {
  int lane = threadIdx.x;
  int okall = 1, cntb = 0;
#pragma unroll
  for (int j = 0; j < 4; ++j) {
    u16 x = w[2 * (lane * 4 + j)];
    int e = (x >> 7) & 0xFF;
    int bok = (e >= 60 && e <= 126);
    int zok = (e == 0);
    okall &= (bok | zok);
    cntb += bok;
  }
  unsigned long long b1 = __ballot(okall != 0);
  unsigned long long b2 = __ballot(cntb >= 3);
  if (lane == 0)
    *flag = (b1 == ~0ull && __popcll(b2) >= 48) ? 0 : 1;
}

// ---------------------------------------------------------------------------
// cvt_pack: fragment-major weight panels from [W_hh | W_dec] (verified).
// ---------------------------------------------------------------------------
__global__ __launch_bounds__(256) void cvt_pack_kernel(
    const void* __restrict__ Whh, const void* __restrict__ Wdec,
    bf* __restrict__ PH, bf* __restrict__ PL,
    const int* __restrict__ flag) {
  int isf = *flag;
  long n8 = (long)NCOL * NG / 8;             // 2,359,296 groups
  long i = (long)blockIdx.x * 256 + threadIdx.x;
  long stride = (long)gridDim.x * 256;
  for (; i < n8; i += stride) {
    int lane = (int)(i & 63);
    int kk   = (int)((i >> 6) & 127);
    int strip= (int)(i >> 13);
    int col  = strip * 16 + (lane & 15);
    int k0   = kk * 32 + (lane >> 4) * 8;
    const void* W = (col < NG) ? Whh : Wdec;
    long src = (long)((col < NG) ? col : col - NG) * NG + k0;
    if (isf) {
      const float* ps = (const float*)W + src;
      float4 x = *(const float4*)ps, y = *(const float4*)(ps + 4);
      float xs[8] = {x.x, x.y, x.z, x.w, y.x, y.y, y.z, y.w};
      bf16x8 h, l;
#pragma unroll
      for (int j = 0; j < 8; ++j) {
        bf hh = __float2bfloat16(xs[j]);
        bf ll = __float2bfloat16(xs[j] - __bfloat162float(hh));
        h[j] = *reinterpret_cast<__bf16*>(&hh);
        l[j] = *reinterpret_cast<__bf16*>(&ll);
      }
      *reinterpret_cast<bf16x8*>(PH + i * 8) = h;
      *reinterpret_cast<bf16x8*>(PL + i * 8) = l;
    } else {
      *reinterpret_cast<bf16x8*>(PH + i * 8) =
          *reinterpret_cast<const bf16x8*>((const bf*)W + src);
    }
  }
}

// ---------------------------------------------------------------------------
// init: h0 = p0 @ W_init.T -> Q-layout hi/lo; zero sync. (va/zp now live in
// loop_kernel registers — arrays removed.) Arithmetic identical to verified.
// ---------------------------------------------------------------------------
__global__ __launch_bounds__(256) void init_kernel(
    const void* __restrict__ p0, const void* __restrict__ Winit,
    const int* __restrict__ flag,
    bf* __restrict__ hi0, bf* __restrict__ lo0,
    int* __restrict__ sync)
{
  if (blockIdx.x == 0 && threadIdx.x == 0) { sync[0] = 0; sync[16] = 0; }
  int isf = *flag;
  int g = blockIdx.x * 4 + (threadIdx.x >> 6);   // wave id 0..32767
  int lane = threadIdx.x & 63;
  int b  = g >> 9;                               // 0..63
  int n0 = g & 511;
  float pf[8];
  if (isf) {
    const float* pp = (const float*)p0 + (long)b * NP + lane * 8;
    float4 x = *(const float4*)pp, y = *(const float4*)(pp + 4);
    pf[0]=x.x; pf[1]=x.y; pf[2]=x.z; pf[3]=x.w;
    pf[4]=y.x; pf[5]=y.y; pf[6]=y.z; pf[7]=y.w;
  } else {
    bf16x8 a = ldfrag((const bf*)p0 + (long)b * NP + lane * 8);
#pragma unroll
    for (int j = 0; j < 8; ++j) pf[j] = (float)a[j];
  }
#pragma unroll
  for (int it = 0; it < 8; ++it) {
    int n = n0 + (it << 9);
    float acc;
    if (isf) {
      const float* pw = (const float*)Winit + (long)n * NP + lane * 8;
      float4 x = *(const float4*)pw, y = *(const float4*)(pw + 4);
      acc = pf[0]*x.x + pf[1]*x.y + pf[2]*x.z + pf[3]*x.w
          + pf[4]*y.x + pf[5]*y.y + pf[6]*y.z + pf[7]*y.w;
    } else {
      bf16x8 wv = ldfrag((const bf*)Winit + (long)n * NP + lane * 8);
      acc = 0.f;
#pragma unroll
      for (int j = 0; j < 8; ++j) acc += pf[j] * (float)wv[j];
    }
#pragma unroll
    for (int s = 32; s >= 1; s >>= 1) acc += __shfl_xor(acc, s, 64);
    if (lane == 0) {
      bf h = __float2bfloat16(acc);
      float lo = isf ? (acc - __bfloat162float(h)) : 0.f;
      long q = qidx(b, n);
      hi0[q] = h;
      lo0[q] = __float2bfloat16(lo);
    }
  }
}

// ---------------------------------------------------------------------------
// loop: persistent, B-PANEL PINNED IN LDS. 256 blocks x 512 thr, 1 block/CU.
// R12 showed FETCH = 43 MB/step: the panel re-streams from beyond L2 every
// step (panel 37.75 MB > 32 MB aggregate L2, plus the barrier's device-scope
// acquire fence invalidates L2 each step) at latency-bound ~1 TB/s — the
// ~30-44 us/step invariant of ALL structures. LDS is immune to both: stage
// each z-strip's 128 KB panel into LDS ONCE, reuse for all 101 steps.
// Block b: z-strip b (4096 = 256 x 16 cols); blocks 0..31 also run dec strip
// 256+b with a streamed panel (4 MB/step, L2/L3-resident). va/zp live in 4
// regs/thread (same (m,c) every step) — state traffic eliminated.
// MFMA chain order, ks-sum order, epilogue math: bit-identical to verified.
// red[8][32][17] two-pass (chains 0,1 -> m0..31; 2,3 -> m32..63), pad 17
// fixes R12's 7.37M bank conflicts. LDS total 148 KB -> exactly 1 block/CU,
// 256 blocks co-resident -> ticket barrier (R12-proven) is deadlock-free.
// ---------------------------------------------------------------------------
__global__ __launch_bounds__(512, 2) void loop_kernel(
    bf* __restrict__ hi0, bf* __restrict__ hi1,
    bf* __restrict__ lo0, bf* __restrict__ lo1,
    const bf* __restrict__ PH, const bf* __restrict__ PL,
    const void* __restrict__ Wih, const void* __restrict__ vin,
    const int* __restrict__ flag, void* __restrict__ out,
    int* __restrict__ sync)
{
  int strip = blockIdx.x;              // z-strip 0..255
  int isf = *flag;
  int tid  = threadIdx.x;
  int ks   = tid >> 6;                 // 0..7
  int lane = tid & 63;
  int quad = lane >> 4, l16 = lane & 15;
  int* cnt = sync;
  int* gen = sync + 16;

  __shared__ __align__(16) bf    panel[128 * 512];   // 128 KB: this strip's B
  __shared__ __align__(16) float red[NKS][32][17];   // 17.4 KB, padded

  // Stage this z-strip's panel once (bf16 mode only; fp32 streams global).
  if (!isf) {
    const bf16x8* src = (const bf16x8*)(PH + (long)strip * 65536);
    bf16x8* dst = (bf16x8*)panel;
    for (int i = tid; i < 8192; i += 512) dst[i] = src[i];
  }
  __syncthreads();

  // Per-thread persistent epilogue state: element (m, c) fixed across steps.
  int ml  = tid >> 4;                  // 0..31
  int c16 = tid & 15;
  int cz  = strip * 16 + c16;          // this thread's z-column
  float w0 = ldin(Wih, 2L * cz, isf);
  float w1 = ldin(Wih, 2L * cz + 1, isf);
  float va0 = 0.f, zp0 = 0.f;          // element (ml,      cz)
  float va1 = 0.f, zp1 = 0.f;          // element (ml + 32, cz)

  const bf* pBd  = PH + ((long)(256 + strip) * 128 + ks * 16) * 512 + lane * 8;
  const bf* pBdl = PL + ((long)(256 + strip) * 128 + ks * 16) * 512 + lane * 8;

  for (int t = 0; t <= TT; ++t) {
    const bf* Qh = (t & 1) ? hi1 : hi0;
    const bf* Ql = (t & 1) ? lo1 : lo0;
    bf* hN = (t & 1) ? hi0 : hi1;
    bf* lN = (t & 1) ? lo0 : lo1;

    // ---------------- z-strip GEMM + epilogue (t < TT) ----------------
    if (t != TT) {
      const bf* pA = Qh + (long)ks * 32768 + lane * 8;
      f32x4 acc0 = {0.f,0.f,0.f,0.f}, acc1 = acc0, acc2 = acc0, acc3 = acc0;
      if (isf) {
        const bf* pB  = PH + ((long)strip * 128 + ks * 16) * 512 + lane * 8;
        const bf* pBl = PL + ((long)strip * 128 + ks * 16) * 512 + lane * 8;
        const bf* pAl = Ql + (long)ks * 32768 + lane * 8;
#pragma unroll 2
        for (int i = 0; i < 16; ++i) {
          bf16x8 bh = ldfrag(pB  + i * 512);
          bf16x8 bl = ldfrag(pBl + i * 512);
          const bf* ah = pA  + i * 2048;
          const bf* al = pAl + i * 2048;
          bf16x8 a0 = ldfrag(ah);
          bf16x8 a1 = ldfrag(ah + 512);
          bf16x8 a2 = ldfrag(ah + 1024);
          bf16x8 a3 = ldfrag(ah + 1536);
          bf16x8 l0 = ldfrag(al);
          bf16x8 l1 = ldfrag(al + 512);
          bf16x8 l2 = ldfrag(al + 1024);
          bf16x8 l3 = ldfrag(al + 1536);
          acc0 = mfma16(a0, bh, acc0); acc0 = mfma16(l0, bh, acc0); acc0 = mfma16(a0, bl, acc0);
          acc1 = mfma16(a1, bh, acc1); acc1 = mfma16(l1, bh, acc1); acc1 = mfma16(a1, bl, acc1);
          acc2 = mfma16(a2, bh, acc2); acc2 = mfma16(l2, bh, acc2); acc2 = mfma16(a2, bl, acc2);
          acc3 = mfma16(a3, bh, acc3); acc3 = mfma16(l3, bh, acc3); acc3 = mfma16(a3, bl, acc3);
        }
      } else {
        const bf* lB = panel + ks * 8192 + lane * 8;   // LDS-pinned panel
#pragma unroll 4
        for (int i = 0; i < 16; ++i) {
          bf16x8 bh = ldfrag(lB + i * 512);
          const bf* ah = pA + i * 2048;
          acc0 = mfma16(ldfrag(ah),        bh, acc0);
          acc1 = mfma16(ldfrag(ah + 512),  bh, acc1);
          acc2 = mfma16(ldfrag(ah + 1024), bh, acc2);
          acc3 = mfma16(ldfrag(ah + 1536), bh, acc3);
        }
      }

      // two-pass reduce+epilogue; C/D layout (verified): m = mt*16+quad*4+r.
#pragma unroll
      for (int half = 0; half < 2; ++half) {
        __syncthreads();               // prior red readers done
        f32x4 ca = (half == 0) ? acc0 : acc2;
        f32x4 cb = (half == 0) ? acc1 : acc3;
#pragma unroll
        for (int r = 0; r < 4; ++r) {
          red[ks][quad * 4 + r][l16]      = ca[r];
          red[ks][16 + quad * 4 + r][l16] = cb[r];
        }
        __syncthreads();
        int m = half * 32 + ml;
        float z = 0.f;
#pragma unroll
        for (int k2 = 0; k2 < NKS; ++k2)   // same ks order as verified
          z += red[k2][ml][c16];
        float v0 = ldin(vin, ((long)m * TT + t) * 2, isf);
        float v1 = ldin(vin, ((long)m * TT + t) * 2 + 1, isf);
        float vao = half ? va1 : va0;
        float zpo = half ? zp1 : zp0;
        float s;
        if (isf) {
          z += v0 * w0 + v1 * w1;
          z -= 0.1f * vao;                       // OLD va
          float van = vao + 0.9f * (zpo - vao);  // OLD zp
          if (half) { va1 = van; zp1 = z; } else { va0 = van; zp0 = z; }
          s = fmaxf(z, 0.f);
          bf sh = __float2bfloat16(s);
          long q = qidx(m, cz);
          hN[q] = sh;
          lN[q] = __float2bfloat16(s - __bfloat162float(sh));
        } else {
          // stepwise bf16 requantization (verified vs XLA bf16 reference)
          float zmm = bfr(z);
          float zv  = bfr(v0 * w0 + v1 * w1);
          float z0  = bfr(zmm + zv);
          float sub = bfr(ALPHA_BF * vao);
          float z1  = bfr(z0 - sub);
          float d   = bfr(zpo - vao);
          float mm  = bfr(BETA_BF * d);
          float van = bfr(vao + mm);
          if (half) { va1 = van; zp1 = z1; } else { va0 = van; zp0 = z1; }
          s = fmaxf(z1, 0.f);
          long q = qidx(m, cz);
          hN[q] = __float2bfloat16(s);
          lN[q] = __float2bfloat16(0.f);
        }
      }
    }

    // ---------------- dec strip (blocks 0..31, t > 0), streamed ----------
    if (strip < 32 && t != 0) {
      const bf* pA = Qh + (long)ks * 32768 + lane * 8;
      f32x4 acc0 = {0.f,0.f,0.f,0.f}, acc1 = acc0, acc2 = acc0, acc3 = acc0;
      if (isf) {
        const bf* pAl = Ql + (long)ks * 32768 + lane * 8;
#pragma unroll 2
        for (int i = 0; i < 16; ++i) {
          bf16x8 bh = ldfrag(pBd  + i * 512);
          bf16x8 bl = ldfrag(pBdl + i * 512);
          const bf* ah = pA  + i * 2048;
          const bf* al = pAl + i * 2048;
          bf16x8 a0 = ldfrag(ah);
          bf16x8 a1 = ldfrag(ah + 512);
          bf16x8 a2 = ldfrag(ah + 1024);
          bf16x8 a3 = ldfrag(ah + 1536);
          bf16x8 l0 = ldfrag(al);
          bf16x8 l1 = ldfrag(al + 512);
          bf16x8 l2 = ldfrag(al + 1024);
          bf16x8 l3 = ldfrag(al + 1536);
          acc0 = mfma16(a0, bh, acc0); acc0 = mfma16(l0, bh, acc0); acc0 = mfma16(a0, bl, acc0);
          acc1 = mfma16(a1, bh, acc1); acc1 = mfma16(l1, bh, acc1); acc1 = mfma16(a1, bl, acc1);
          acc2 = mfma16(a2, bh, acc2); acc2 = mfma16(l2, bh, acc2); acc2 = mfma16(a2, bl, acc2);
          acc3 = mfma16(a3, bh, acc3); acc3 = mfma16(l3, bh, acc3); acc3 = mfma16(a3, bl, acc3);
        }
      } else {
#pragma unroll 4
        for (int i = 0; i < 16; ++i) {
          bf16x8 bh = ldfrag(pBd + i * 512);
          const bf* ah = pA + i * 2048;
          acc0 = mfma16(ldfrag(ah),        bh, acc0);
          acc1 = mfma16(ldfrag(ah + 512),  bh, acc1);
          acc2 = mfma16(ldfrag(ah + 1024), bh, acc2);
          acc3 = mfma16(ldfrag(ah + 1536), bh, acc3);
        }
      }
#pragma unroll
      for (int half = 0; half < 2; ++half) {
        __syncthreads();
        f32x4 ca = (half == 0) ? acc0 : acc2;
        f32x4 cb = (half == 0) ? acc1 : acc3;
#pragma unroll
        for (int r = 0; r < 4; ++r) {
          red[ks][quad * 4 + r][l16]      = ca[r];
          red[ks][16 + quad * 4 + r][l16] = cb[r];
        }
        __syncthreads();
        int m = half * 32 + ml;
        float z = 0.f;
#pragma unroll
        for (int k2 = 0; k2 < NKS; ++k2)
          z += red[k2][ml][c16];
        long o = ((long)m * TT + (t - 1)) * NP + strip * 16 + c16;
        if (isf) ((float*)out)[o] = z;
        else     ((bf*)out)[o]    = __float2bfloat16(z);
      }
    }

    gridbar(cnt, gen, t);              // all 256 blocks, every t
  }
}

// ---------------------------------------------------------------------------
extern "C" void kernel_launch(void* const* d_in, const int* in_sizes, int n_in,
                              void* d_out, int out_size, void* d_ws, size_t ws_size,
                              hipStream_t stream) {
  const void* v     = d_in[0];   // [64,100,2]
  const void* p0    = d_in[1];   // [64,512]
  const void* Winit = d_in[2];   // [4096,512]
  const void* Wih   = d_in[3];   // [4096,2]
  const void* Whh   = d_in[4];   // [4096,4096]
  const void* Wdec  = d_in[5];   // [512,4096]

  size_t off = 0;
  char* w = (char*)d_ws;
  int*   flag = (int*)(w + off);          off += 64;
  bf*    PH   = (bf*)(w + off);           off += (size_t)NCOL * NG * 2;  // 37.75 MB
  bf*    PL   = (bf*)(w + off);           off += (size_t)NCOL * NG * 2;
  bf* hi0 = (bf*)(w + off);               off += (size_t)64 * NG * 2;
  bf* hi1 = (bf*)(w + off);               off += (size_t)64 * NG * 2;
  bf* lo0 = (bf*)(w + off);               off += (size_t)64 * NG * 2;
  bf* lo1 = (bf*)(w + off);               off += (size_t)64 * NG * 2;
  int*   sync = (int*)(w + off);          off += 128;

  if (ws_size < off) return;

  probe_kernel<<<1, 64, 0, stream>>>((const u16*)Whh, flag);
  cvt_pack_kernel<<<9216, 256, 0, stream>>>(Whh, Wdec, PH, PL, flag);
  init_kernel<<<8192, 256, 0, stream>>>(p0, Winit, flag, hi0, lo0, sync);
  loop_kernel<<<NBLK, 512, 0, stream>>>(hi0, hi1, lo0, lo1,
                                        PH, PL, Wih, v, flag, d_out, sync);
}

// Round 14
// 2585.449 us; speedup vs baseline: 1.7647x; 1.7256x over previous
//
#include <hip/hip_runtime.h>
#include <hip/hip_bf16.h>

#define NG 4096
#define NP 512
#define TT 100
#define NCOL 4608            // 4096 z-cols + 512 dec-cols (panel layout)
#define NKS 8                // K-splits (512 each)
#define PLANE 262144L        // 64*4096 elems per h-plane

typedef __bf16  bf16x8 __attribute__((ext_vector_type(8)));
typedef float   f32x4  __attribute__((ext_vector_type(4)));
typedef __hip_bfloat16 bf;
typedef unsigned short u16;

#define ALPHA_BF 0.10009765625f   // bf16(0.1)
#define BETA_BF  0.8984375f       // bf16(0.9)

__device__ __forceinline__ bf16x8 ldfrag(const bf* p) {
  return *reinterpret_cast<const bf16x8*>(p);
}
__device__ __forceinline__ f32x4 mfma16(bf16x8 a, bf16x8 b, f32x4 c) {
  return __builtin_amdgcn_mfma_f32_16x16x32_bf16(a, b, c, 0, 0, 0);
}
__device__ __forceinline__ float ldin(const void* p, long i, int isf) {
  return isf ? ((const float*)p)[i] : __bfloat162float(((const bf*)p)[i]);
}
__device__ __forceinline__ float bfr(float x) {
  return __bfloat162float(__float2bfloat16(x));
}
// Fragment-major index for the hidden state Q[kk][mt][lane][8] (verified).
__device__ __forceinline__ long qidx(int m, int c) {
  int kk = c >> 5, qd = (c >> 3) & 3, j = c & 7;
  int mt = m >> 4, lm = m & 15;
  return (((long)kk * 4 + mt) * 64 + (qd * 16 + lm)) * 8 + j;
}

// ---------------------------------------------------------------------------
// Probe: fp32 (flag=1) vs bf16 (flag=0) inputs. Verified many rounds.
// ---------------------------------------------------------------------------
__global__ void probe_kernel(const u16* __restrict__ w, int* __restrict__ flag) {
  int lane = threadIdx.x;
  int okall = 1, cntb = 0;
#pragma unroll
  for (int j = 0; j < 4; ++j) {
    u16 x = w[2 * (lane * 4 + j)];
    int e = (x >> 7) & 0xFF;
    int bok = (e >= 60 && e <= 126);
    int zok = (e == 0);
    okall &= (bok | zok);
    cntb += bok;
  }
  unsigned long long b1 = __ballot(okall != 0);
  unsigned long long b2 = __ballot(cntb >= 3);
  if (lane == 0)
    *flag = (b1 == ~0ull && __popcll(b2) >= 48) ? 0 : 1;
}

// ---------------------------------------------------------------------------
// cvt_pack: fragment-major weight panels from [W_hh | W_dec] (verified).
// ---------------------------------------------------------------------------
__global__ __launch_bounds__(256) void cvt_pack_kernel(
    const void* __restrict__ Whh, const void* __restrict__ Wdec,
    bf* __restrict__ PH, bf* __restrict__ PL,
    const int* __restrict__ flag) {
  int isf = *flag;
  long n8 = (long)NCOL * NG / 8;             // 2,359,296 groups
  long i = (long)blockIdx.x * 256 + threadIdx.x;
  long stride = (long)gridDim.x * 256;
  for (; i < n8; i += stride) {
    int lane = (int)(i & 63);
    int kk   = (int)((i >> 6) & 127);
    int strip= (int)(i >> 13);
    int col  = strip * 16 + (lane & 15);
    int k0   = kk * 32 + (lane >> 4) * 8;
    const void* W = (col < NG) ? Whh : Wdec;
    long src = (long)((col < NG) ? col : col - NG) * NG + k0;
    if (isf) {
      const float* ps = (const float*)W + src;
      float4 x = *(const float4*)ps, y = *(const float4*)(ps + 4);
      float xs[8] = {x.x, x.y, x.z, x.w, y.x, y.y, y.z, y.w};
      bf16x8 h, l;
#pragma unroll
      for (int j = 0; j < 8; ++j) {
        bf hh = __float2bfloat16(xs[j]);
        bf ll = __float2bfloat16(xs[j] - __bfloat162float(hh));
        h[j] = *reinterpret_cast<__bf16*>(&hh);
        l[j] = *reinterpret_cast<__bf16*>(&ll);
      }
      *reinterpret_cast<bf16x8*>(PH + i * 8) = h;
      *reinterpret_cast<bf16x8*>(PL + i * 8) = l;
    } else {
      *reinterpret_cast<bf16x8*>(PH + i * 8) =
          *reinterpret_cast<const bf16x8*>((const bf*)W + src);
      // PL untouched: bf16 mode never reads it.
    }
  }
}

// ---------------------------------------------------------------------------
// init: h0 = p0 @ W_init.T -> plane 0 of g (Q-layout hi/lo); zero va/zp.
// Coalesced wave-dot, 8 rows/wave. Arithmetic identical to verified.
// ---------------------------------------------------------------------------
__global__ __launch_bounds__(256) void init_kernel(
    const void* __restrict__ p0, const void* __restrict__ Winit,
    const int* __restrict__ flag,
    bf* __restrict__ ghi, bf* __restrict__ glo,
    float* __restrict__ va, float* __restrict__ zp)
{
  int isf = *flag;
  int g = blockIdx.x * 4 + (threadIdx.x >> 6);   // wave id 0..32767
  int lane = threadIdx.x & 63;
  int b  = g >> 9;                               // 0..63
  int n0 = g & 511;
  float pf[8];
  if (isf) {
    const float* pp = (const float*)p0 + (long)b * NP + lane * 8;
    float4 x = *(const float4*)pp, y = *(const float4*)(pp + 4);
    pf[0]=x.x; pf[1]=x.y; pf[2]=x.z; pf[3]=x.w;
    pf[4]=y.x; pf[5]=y.y; pf[6]=y.z; pf[7]=y.w;
  } else {
    bf16x8 a = ldfrag((const bf*)p0 + (long)b * NP + lane * 8);
#pragma unroll
    for (int j = 0; j < 8; ++j) pf[j] = (float)a[j];
  }
#pragma unroll
  for (int it = 0; it < 8; ++it) {
    int n = n0 + (it << 9);
    float acc;
    if (isf) {
      const float* pw = (const float*)Winit + (long)n * NP + lane * 8;
      float4 x = *(const float4*)pw, y = *(const float4*)(pw + 4);
      acc = pf[0]*x.x + pf[1]*x.y + pf[2]*x.z + pf[3]*x.w
          + pf[4]*y.x + pf[5]*y.y + pf[6]*y.z + pf[7]*y.w;
    } else {
      bf16x8 wv = ldfrag((const bf*)Winit + (long)n * NP + lane * 8);
      acc = 0.f;
#pragma unroll
      for (int j = 0; j < 8; ++j) acc += pf[j] * (float)wv[j];
    }
#pragma unroll
    for (int s = 32; s >= 1; s >>= 1) acc += __shfl_xor(acc, s, 64);
    if (lane == 0) {
      bf h = __float2bfloat16(acc);
      long q = qidx(b, n);
      ghi[q] = h;
      if (isf) glo[q] = __float2bfloat16(acc - __bfloat162float(h));
      long idx = (long)b * NG + n;
      va[idx] = 0.f;
      zp[idx] = 0.f;
    }
  }
}

// ---------------------------------------------------------------------------
// s12: fused recurrence step, Z-STRIPS ONLY. 256 blocks x 512 thr = EXACT
// 1 block/CU packing (dec work deferred to dec_kernel -> no 288-on-256
// makespan tail, no part[] round-trip, B-panel read exactly once).
// Block = strip; wave = ks; 4 acc chains (all 64 m) — MFMA chain order and
// ks-sum order 0..7 bit-identical to verified rounds. red padded [17].
// Per-step L3 traffic: B 32 MB + A ~4 MB + state 6 MB  (was ~90 MB).
// ---------------------------------------------------------------------------
__global__ __launch_bounds__(512, 4) void s12_kernel(
    const bf* __restrict__ Qh, const bf* __restrict__ Ql,
    bf* __restrict__ hN, bf* __restrict__ lN,
    float* __restrict__ va, float* __restrict__ zp,
    const bf* __restrict__ PH, const bf* __restrict__ PL,
    const void* __restrict__ Wih, const void* __restrict__ vin,
    const int* __restrict__ flag, int t)
{
  int strip = blockIdx.x;              // z-strip 0..255
  int isf = *flag;
  int tid  = threadIdx.x;
  int ks   = tid >> 6;                 // 0..7
  int lane = tid & 63;
  int quad = lane >> 4, l16 = lane & 15;

  const bf* pB = PH + ((long)strip * 128 + ks * 16) * 512 + lane * 8;
  const bf* pA = Qh + (long)ks * 32768 + lane * 8;

  f32x4 acc0 = {0.f,0.f,0.f,0.f}, acc1 = acc0, acc2 = acc0, acc3 = acc0;
  if (isf) {
    const bf* pBl = PL + ((long)strip * 128 + ks * 16) * 512 + lane * 8;
    const bf* pAl = Ql + (long)ks * 32768 + lane * 8;
#pragma unroll 2
    for (int i = 0; i < 16; ++i) {
      bf16x8 bh = ldfrag(pB  + i * 512);
      bf16x8 bl = ldfrag(pBl + i * 512);
      const bf* ah = pA  + i * 2048;
      const bf* al = pAl + i * 2048;
      bf16x8 a0 = ldfrag(ah);
      bf16x8 a1 = ldfrag(ah + 512);
      bf16x8 a2 = ldfrag(ah + 1024);
      bf16x8 a3 = ldfrag(ah + 1536);
      bf16x8 l0 = ldfrag(al);
      bf16x8 l1 = ldfrag(al + 512);
      bf16x8 l2 = ldfrag(al + 1024);
      bf16x8 l3 = ldfrag(al + 1536);
      acc0 = mfma16(a0, bh, acc0); acc0 = mfma16(l0, bh, acc0); acc0 = mfma16(a0, bl, acc0);
      acc1 = mfma16(a1, bh, acc1); acc1 = mfma16(l1, bh, acc1); acc1 = mfma16(a1, bl, acc1);
      acc2 = mfma16(a2, bh, acc2); acc2 = mfma16(l2, bh, acc2); acc2 = mfma16(a2, bl, acc2);
      acc3 = mfma16(a3, bh, acc3); acc3 = mfma16(l3, bh, acc3); acc3 = mfma16(a3, bl, acc3);
    }
  } else {
#pragma unroll 4
    for (int i = 0; i < 16; ++i) {
      bf16x8 bh = ldfrag(pB + i * 512);
      const bf* ah = pA + i * 2048;
      acc0 = mfma16(ldfrag(ah),        bh, acc0);
      acc1 = mfma16(ldfrag(ah + 512),  bh, acc1);
      acc2 = mfma16(ldfrag(ah + 1024), bh, acc2);
      acc3 = mfma16(ldfrag(ah + 1536), bh, acc3);
    }
  }

  // C/D layout (verified): col=l16, row=quad*4+r; m = mt*16 + quad*4 + r.
  __shared__ float red[NKS][64][17];   // padded: kills 4-way write conflicts
#pragma unroll
  for (int mt = 0; mt < 4; ++mt) {
    f32x4 a = (mt == 0) ? acc0 : (mt == 1) ? acc1 : (mt == 2) ? acc2 : acc3;
#pragma unroll
    for (int r = 0; r < 4; ++r)
      red[ks][mt * 16 + quad * 4 + r][l16] = a[r];
  }
  __syncthreads();

  // epilogue: 1024 elems (64 m x 16 cols), 2 per thread — verified s2 math.
#pragma unroll
  for (int half = 0; half < 2; ++half) {
    int e = half * 512 + tid;          // 0..1023
    int m   = e >> 4;                  // batch row 0..63
    int c16 = e & 15;
    int c = strip * 16 + c16;          // z-column 0..4095
    float z = 0.f;
#pragma unroll
    for (int k2 = 0; k2 < NKS; ++k2)   // same ks order as verified
      z += red[k2][m][c16];

    float w0 = ldin(Wih, 2L * c, isf);
    float w1 = ldin(Wih, 2L * c + 1, isf);
    float v0 = ldin(vin, ((long)m * TT + t) * 2, isf);
    float v1 = ldin(vin, ((long)m * TT + t) * 2 + 1, isf);
    long idx = (long)m * NG + c;
    float vao = va[idx], zpo = zp[idx];
    if (isf) {
      z += v0 * w0 + v1 * w1;
      z -= 0.1f * vao;                      // subtract uses OLD va
      va[idx] = vao + 0.9f * (zpo - vao);   // adaptation uses OLD zp
      zp[idx] = z;                          // z_prev = post-subtraction z
      float s = fmaxf(z, 0.f);
      bf sh = __float2bfloat16(s);
      long q = qidx(m, c);
      hN[q] = sh;
      lN[q] = __float2bfloat16(s - __bfloat162float(sh));
    } else {
      // stepwise bf16 requantization (matches XLA bf16 reference; verified)
      float zmm = bfr(z);                   // bf16(h @ Whh.T)
      float zv  = bfr(v0 * w0 + v1 * w1);   // bf16(v_t @ Wih.T)
      float z0  = bfr(zmm + zv);            // bf16 add
      float sub = bfr(ALPHA_BF * vao);      // bf16(bf16(0.1) * va)
      float z1  = bfr(z0 - sub);            // post-subtraction z (bf16)
      float d   = bfr(zpo - vao);           // bf16(zp - va)
      float mm  = bfr(BETA_BF * d);         // bf16(bf16(0.9) * d)
      va[idx]   = bfr(vao + mm);
      zp[idx]   = z1;
      float s = fmaxf(z1, 0.f);
      long q = qidx(m, c);
      hN[q] = __float2bfloat16(s);          // exact; bf16 mode: lo == 0, unread
    }
  }
}

// ---------------------------------------------------------------------------
// dec: batch decoder GEMM, once after the loop. out[:,t,:] = s_t @ Wdec.T,
// s_t = g plane t+1. Grid (32 dec-strips, 100 t) x 512 thr; same fused
// block structure (8 ks waves, 4 chains, LDS reduce, same ks-sum order).
// Fully parallel: 3200 blocks, no serial dependence — runs at GEMM rates.
// ---------------------------------------------------------------------------
__global__ __launch_bounds__(512, 4) void dec_kernel(
    const bf* __restrict__ ghi, const bf* __restrict__ glo,
    const bf* __restrict__ PH, const bf* __restrict__ PL,
    const int* __restrict__ flag, void* __restrict__ out)
{
  int strip = blockIdx.x;              // dec strip 0..31
  int t     = blockIdx.y;              // 0..99
  int isf = *flag;
  int tid  = threadIdx.x;
  int ks   = tid >> 6;
  int lane = tid & 63;
  int quad = lane >> 4, l16 = lane & 15;

  const bf* Qh = ghi + (long)(t + 1) * PLANE;
  const bf* pB = PH + ((long)(256 + strip) * 128 + ks * 16) * 512 + lane * 8;
  const bf* pA = Qh + (long)ks * 32768 + lane * 8;

  f32x4 acc0 = {0.f,0.f,0.f,0.f}, acc1 = acc0, acc2 = acc0, acc3 = acc0;
  if (isf) {
    const bf* Ql = glo + (long)(t + 1) * PLANE;
    const bf* pBl = PL + ((long)(256 + strip) * 128 + ks * 16) * 512 + lane * 8;
    const bf* pAl = Ql + (long)ks * 32768 + lane * 8;
#pragma unroll 2
    for (int i = 0; i < 16; ++i) {
      bf16x8 bh = ldfrag(pB  + i * 512);
      bf16x8 bl = ldfrag(pBl + i * 512);
      const bf* ah = pA  + i * 2048;
      const bf* al = pAl + i * 2048;
      bf16x8 a0 = ldfrag(ah);
      bf16x8 a1 = ldfrag(ah + 512);
      bf16x8 a2 = ldfrag(ah + 1024);
      bf16x8 a3 = ldfrag(ah + 1536);
      bf16x8 l0 = ldfrag(al);
      bf16x8 l1 = ldfrag(al + 512);
      bf16x8 l2 = ldfrag(al + 1024);
      bf16x8 l3 = ldfrag(al + 1536);
      acc0 = mfma16(a0, bh, acc0); acc0 = mfma16(l0, bh, acc0); acc0 = mfma16(a0, bl, acc0);
      acc1 = mfma16(a1, bh, acc1); acc1 = mfma16(l1, bh, acc1); acc1 = mfma16(a1, bl, acc1);
      acc2 = mfma16(a2, bh, acc2); acc2 = mfma16(l2, bh, acc2); acc2 = mfma16(a2, bl, acc2);
      acc3 = mfma16(a3, bh, acc3); acc3 = mfma16(l3, bh, acc3); acc3 = mfma16(a3, bl, acc3);
    }
  } else {
#pragma unroll 4
    for (int i = 0; i < 16; ++i) {
      bf16x8 bh = ldfrag(pB + i * 512);
      const bf* ah = pA + i * 2048;
      acc0 = mfma16(ldfrag(ah),        bh, acc0);
      acc1 = mfma16(ldfrag(ah + 512),  bh, acc1);
      acc2 = mfma16(ldfrag(ah + 1024), bh, acc2);
      acc3 = mfma16(ldfrag(ah + 1536), bh, acc3);
    }
  }

  __shared__ float red[NKS][64][17];
#pragma unroll
  for (int mt = 0; mt < 4; ++mt) {
    f32x4 a = (mt == 0) ? acc0 : (mt == 1) ? acc1 : (mt == 2) ? acc2 : acc3;
#pragma unroll
    for (int r = 0; r < 4; ++r)
      red[ks][mt * 16 + quad * 4 + r][l16] = a[r];
  }
  __syncthreads();

#pragma unroll
  for (int half = 0; half < 2; ++half) {
    int e = half * 512 + tid;
    int m   = e >> 4;
    int c16 = e & 15;
    float z = 0.f;
#pragma unroll
    for (int k2 = 0; k2 < NKS; ++k2)   // same ks order as verified
      z += red[k2][m][c16];
    long o = ((long)m * TT + t) * NP + strip * 16 + c16;
    if (isf) ((float*)out)[o] = z;
    else     ((bf*)out)[o]    = __float2bfloat16(z);
  }
}

// ---------------------------------------------------------------------------
extern "C" void kernel_launch(void* const* d_in, const int* in_sizes, int n_in,
                              void* d_out, int out_size, void* d_ws, size_t ws_size,
                              hipStream_t stream) {
  const void* v     = d_in[0];   // [64,100,2]
  const void* p0    = d_in[1];   // [64,512]
  const void* Winit = d_in[2];   // [4096,512]
  const void* Wih   = d_in[3];   // [4096,2]
  const void* Whh   = d_in[4];   // [4096,4096]
  const void* Wdec  = d_in[5];   // [512,4096]

  size_t off = 0;
  char* w = (char*)d_ws;
  int*   flag = (int*)(w + off);          off += 64;
  bf*    PH   = (bf*)(w + off);           off += (size_t)NCOL * NG * 2;  // 37.75 MB
  bf*    PL   = (bf*)(w + off);           off += (size_t)NCOL * NG * 2;
  bf*    ghi  = (bf*)(w + off);           off += (size_t)(TT + 1) * PLANE * 2;  // 51.7 MB
  bf*    glo  = (bf*)(w + off);           off += (size_t)(TT + 1) * PLANE * 2;
  float* va   = (float*)(w + off);        off += (size_t)64 * NG * 4;
  float* zp   = (float*)(w + off);        off += (size_t)64 * NG * 4;
  // total ~181 MB

  if (ws_size < off) return;

  probe_kernel<<<1, 64, 0, stream>>>((const u16*)Whh, flag);
  cvt_pack_kernel<<<9216, 256, 0, stream>>>(Whh, Wdec, PH, PL, flag);
  init_kernel<<<8192, 256, 0, stream>>>(p0, Winit, flag, ghi, glo, va, zp);

  for (int t = 0; t < TT; ++t) {
    s12_kernel<<<256, 512, 0, stream>>>(ghi + (long)t * PLANE,
                                        glo + (long)t * PLANE,
                                        ghi + (long)(t + 1) * PLANE,
                                        glo + (long)(t + 1) * PLANE,
                                        va, zp, PH, PL, Wih, v, flag, t);
  }
  dec_kernel<<<dim3(32, TT), 512, 0, stream>>>(ghi, glo, PH, PL, flag, d_out);
}